// Round 7
// baseline (219.886 us; speedup 1.0000x reference)
//
#include <hip/hip_runtime.h>
#include <hip/hip_bf16.h>
#include <math.h>

// Problem: B=4, L=2048 (M = 8192 rows), D_MODEL = 768, N_STATE = 16.
// y[row,d] = x[row,d] * softplus((x@W1+b1)[row,d]) * dot(x@W2+b2, x@W3+b3)[row]
// Ledger: ~44 us harness fill per iter (fixed, 256 MiB poison -> also wipes
// L3). R11 (112.1, best): xb precompute + single-buffer async16 k-loop,
// 128x64 tile. R13/R16/R17: three orthogonal sync-structure attacks (deep
// pipeline, 2x occupancy, dbuf+drain-after-compute) ALL null at ~43-45 us
// gemm -> hypothesis space exhausted; pipe arithmetic leaves ~60% of gemm
// cycles unexplained. R18 (this round): ABLATION PROBE. Three phase-isolating
// dispatches (stage-only x3, compute-only x4, full-no-epilogue x2) run before
// the verified R11 kernel (correctness-carrying, launched last). Per-dispatch
// rocprof durs decompose the 44 us; the ~44 us fill cutoff in top-5 makes
// even invisible probes informative (<44/R per rep).

#define M_ROWS 8192
#define DM 768
#define NS 16

typedef short bf16x8 __attribute__((ext_vector_type(8)));
typedef float f32x4 __attribute__((ext_vector_type(4)));

__device__ __forceinline__ unsigned short f2bf(float f) {
    union { float f; unsigned u; } v; v.f = f;
    unsigned r = v.u + 0x7FFF + ((v.u >> 16) & 1);   // RNE
    return (unsigned short)(r >> 16);
}
__device__ __forceinline__ float bf2f(unsigned short h) {
    union { unsigned u; float f; } v; v.u = ((unsigned)h) << 16; return v.f;
}
__device__ __forceinline__ void async16(const void* g, void* l) {
    __builtin_amdgcn_global_load_lds(
        (const __attribute__((address_space(1))) void*)g,
        (__attribute__((address_space(3))) void*)l,
        16, 0, 0);
}
__device__ __forceinline__ float softplus_fast(float v) {
    return fmaxf(v, 0.f) + __logf(1.f + __expf(-fabsf(v)));
}

// ---- kernel 1: prep (R0-verbatim) ---------------------------------------
__global__ __launch_bounds__(256) void prep_kernel(
    const float* __restrict__ x,
    const float* __restrict__ W1,
    const float* __restrict__ W2,
    const float* __restrict__ W3,
    unsigned short* __restrict__ xb,
    unsigned short* __restrict__ w1t,
    unsigned short* __restrict__ w23t)
{
    __shared__ float tile[32][33];
    const int bid = blockIdx.x;
    const int tid = threadIdx.x;
    if (bid < 32) {
        const int n = bid, i = n >> 1;
        const float* src = (n & 1) ? W3 : W2;
        #pragma unroll
        for (int e = 0; e < 3; ++e) {
            int k = e * 256 + tid;
            w23t[n * DM + k] = f2bf(src[k * NS + i]);
        }
    } else if (bid < 608) {
        const int b2i = bid - 32;
        const int n0 = (b2i % 24) * 32, k0 = (b2i / 24) * 32;
        const int tx = tid & 31, ty = tid >> 5;
        #pragma unroll
        for (int i = 0; i < 4; ++i) {
            int k = ty + i * 8;
            tile[k][tx] = W1[(k0 + k) * DM + n0 + tx];
        }
        __syncthreads();
        #pragma unroll
        for (int i = 0; i < 4; ++i) {
            int n = ty + i * 8;
            w1t[(n0 + n) * DM + k0 + tx] = f2bf(tile[tx][n]);
        }
    } else {
        int i = (bid - 608) * 256 + tid;
        float4 v = ((const float4*)x)[i];
        ushort4 o;
        o.x = f2bf(v.x); o.y = f2bf(v.y); o.z = f2bf(v.z); o.w = f2bf(v.w);
        ((ushort4*)xb)[i] = o;
    }
}

// ---- probe kernel: MODE 1=full-no-epi, 2=stage-only, 3=compute-only -----
// Mirrors the R11 gemm structure exactly (same LDS, same tile, same XCD
// swizzle, same barrier pattern) so per-phase durs are comparable.
template<int MODE, int REPS>
__global__ __launch_bounds__(256) void probe_kernel(
    const unsigned short* __restrict__ xb,
    const unsigned short* __restrict__ w1t,
    const unsigned short* __restrict__ w23t,
    const float* __restrict__ b2, const float* __restrict__ b3,
    float* __restrict__ scratch)
{
    __shared__ unsigned short Al[128 * 64];
    __shared__ unsigned short Bl[64 * 64];
    __shared__ unsigned short Wl[32 * 64];
    __shared__ float spart[2][128];
    const int b = blockIdx.x;
    const int c = b & 7, j = b >> 3;
    const int m0 = (c * 8 + j / 12) * 128;
    const int n0 = (j % 12) * 64;
    const int tid  = threadIdx.x;
    const int lane = tid & 63;
    const int wave = tid >> 6;
    const int wm = wave >> 1, wn = wave & 1;
    const int l15 = lane & 15, quad = lane >> 4;

    f32x4 acc[4][2];
    f32x4 accP[4];
    #pragma unroll
    for (int i = 0; i < 4; ++i) {
        accP[i] = (f32x4){0.f, 0.f, 0.f, 0.f};
        #pragma unroll
        for (int jj = 0; jj < 2; ++jj)
            acc[i][jj] = (f32x4){0.f, 0.f, 0.f, 0.f};
    }

#define STAGE_ALL(K0) do {                                                  \
        _Pragma("unroll")                                                   \
        for (int i_ = 0; i_ < 4; ++i_) {                                    \
            int ch_ = tid + i_ * 256;                                       \
            int r_ = ch_ >> 3, jg_ = (ch_ & 7) ^ (r_ & 7);                  \
            async16(xb + (m0 + r_) * DM + (K0) + jg_ * 8, Al + ch_ * 8);    \
        }                                                                   \
        _Pragma("unroll")                                                   \
        for (int i_ = 0; i_ < 2; ++i_) {                                    \
            int ch_ = tid + i_ * 256;                                       \
            int r_ = ch_ >> 3, jg_ = (ch_ & 7) ^ (r_ & 7);                  \
            async16(w1t + (n0 + r_) * DM + (K0) + jg_ * 8, Bl + ch_ * 8);   \
        }                                                                   \
        {                                                                   \
            int ch_ = tid;                                                  \
            int r_ = ch_ >> 3, jg_ = (ch_ & 7) ^ (r_ & 7);                  \
            async16(w23t + r_ * DM + (K0) + jg_ * 8, Wl + ch_ * 8);         \
        }                                                                   \
    } while (0)

#define COMPUTE_STEP() do {                                                 \
        _Pragma("unroll")                                                   \
        for (int kk = 0; kk < 2; ++kk) {                                    \
            bf16x8 bfr[2], wfr;                                             \
            _Pragma("unroll")                                               \
            for (int jj = 0; jj < 2; ++jj) {                                \
                int rb = wn * 32 + jj * 16 + l15;                           \
                int jb = (kk * 4 + quad) ^ (rb & 7);                        \
                bfr[jj] = *(const bf16x8*)(Bl + rb * 64 + jb * 8);          \
            }                                                               \
            {                                                               \
                int rw = wn * 16 + l15;                                     \
                int jw = (kk * 4 + quad) ^ (rw & 7);                        \
                wfr = *(const bf16x8*)(Wl + rw * 64 + jw * 8);              \
            }                                                               \
            _Pragma("unroll")                                               \
            for (int i = 0; i < 4; ++i) {                                   \
                int rr = wm * 64 + i * 16 + l15;                            \
                int ja = (kk * 4 + quad) ^ (rr & 7);                        \
                bf16x8 af = *(const bf16x8*)(Al + rr * 64 + ja * 8);        \
                _Pragma("unroll")                                           \
                for (int jj = 0; jj < 2; ++jj)                              \
                    acc[i][jj] = __builtin_amdgcn_mfma_f32_16x16x32_bf16(   \
                        af, bfr[jj], acc[i][jj], 0, 0, 0);                  \
                accP[i] = __builtin_amdgcn_mfma_f32_16x16x32_bf16(          \
                    af, wfr, accP[i], 0, 0, 0);                             \
            }                                                               \
        }                                                                   \
    } while (0)

    if constexpr (MODE == 3) {       // compute-only: stage once
        STAGE_ALL(0);
        __syncthreads();
    }

    for (int rep = 0; rep < REPS; ++rep) {
        for (int k0 = 0; k0 < DM; k0 += 64) {
            if constexpr (MODE != 3) STAGE_ALL(k0);
            __syncthreads();
            if constexpr (MODE != 2) COMPUTE_STEP();
            __syncthreads();
        }
    }

    float v = 0.f;
    if constexpr (MODE != 2) {
        #pragma unroll
        for (int i = 0; i < 4; ++i) {
            v += accP[i][0] + accP[i][1] + accP[i][2] + accP[i][3];
            #pragma unroll
            for (int jj = 0; jj < 2; ++jj)
                v += acc[i][jj][0] + acc[i][jj][1] + acc[i][jj][2] + acc[i][jj][3];
        }
    }
    if constexpr (MODE == 1) {       // include s-reduction (non-epilogue cost)
        const int p = wn * 8 + (l15 >> 1);
        const float bB = b2[p], bC = b3[p];
        #pragma unroll
        for (int i = 0; i < 4; ++i) {
            float sacc[4];
            #pragma unroll
            for (int r = 0; r < 4; ++r) {
                float vv = accP[i][r];
                float pv = __shfl_xor(vv, 1, 64);
                sacc[r] = (l15 & 1) ? (pv + bB) * (vv + bC)
                                    : (vv + bB) * (pv + bC);
                sacc[r] += __shfl_xor(sacc[r], 1, 64);
                sacc[r] += __shfl_xor(sacc[r], 2, 64);
                sacc[r] += __shfl_xor(sacc[r], 4, 64);
                sacc[r] += __shfl_xor(sacc[r], 8, 64);
            }
            if (l15 == 0) {
                #pragma unroll
                for (int r = 0; r < 4; ++r)
                    spart[wn][wm * 64 + i * 16 + quad * 4 + r] = 0.5f * sacc[r];
            }
        }
        __syncthreads();
        v += spart[0][lane] + spart[1][lane + 64];
    }
    if constexpr (MODE == 2) {       // keep staged LDS alive
        v = bf2f(Al[tid * 8]) + bf2f(Bl[(tid * 8) & 4095]) + bf2f(Wl[(tid * 8) & 2047]);
    }
    scratch[b * 256 + tid] = v;
#undef STAGE_ALL
#undef COMPUTE_STEP
}

// ---- kernel 2: R11-verbatim fused GEMM (correctness-carrying) -----------
__global__ __launch_bounds__(256) void gemm_fused_kernel(
    const unsigned short* __restrict__ xb,
    const unsigned short* __restrict__ w1t,
    const unsigned short* __restrict__ w23t,
    const float* __restrict__ b1,
    const float* __restrict__ b2, const float* __restrict__ b3,
    float* __restrict__ y)
{
    __shared__ unsigned short Al[128 * 64];
    __shared__ unsigned short Bl[64 * 64];
    __shared__ unsigned short Wl[32 * 64];
    __shared__ float spart[2][128];
    const int b = blockIdx.x;
    const int c = b & 7, j = b >> 3;
    const int m0 = (c * 8 + j / 12) * 128;
    const int n0 = (j % 12) * 64;
    const int tid  = threadIdx.x;
    const int lane = tid & 63;
    const int wave = tid >> 6;
    const int wm = wave >> 1, wn = wave & 1;
    const int l15 = lane & 15, quad = lane >> 4;

    f32x4 acc[4][2];
    f32x4 accP[4];
    #pragma unroll
    for (int i = 0; i < 4; ++i) {
        accP[i] = (f32x4){0.f, 0.f, 0.f, 0.f};
        #pragma unroll
        for (int jj = 0; jj < 2; ++jj)
            acc[i][jj] = (f32x4){0.f, 0.f, 0.f, 0.f};
    }

    for (int k0 = 0; k0 < DM; k0 += 64) {
        #pragma unroll
        for (int i = 0; i < 4; ++i) {
            int ch = tid + i * 256;
            int r = ch >> 3, jg = (ch & 7) ^ (r & 7);
            async16(xb + (m0 + r) * DM + k0 + jg * 8, Al + ch * 8);
        }
        #pragma unroll
        for (int i = 0; i < 2; ++i) {
            int ch = tid + i * 256;
            int r = ch >> 3, jg = (ch & 7) ^ (r & 7);
            async16(w1t + (n0 + r) * DM + k0 + jg * 8, Bl + ch * 8);
        }
        {
            int ch = tid;
            int r = ch >> 3, jg = (ch & 7) ^ (r & 7);
            async16(w23t + r * DM + k0 + jg * 8, Wl + ch * 8);
        }
        __syncthreads();

        #pragma unroll
        for (int kk = 0; kk < 2; ++kk) {
            bf16x8 bfr[2], wfr;
            #pragma unroll
            for (int jj = 0; jj < 2; ++jj) {
                int rb = wn * 32 + jj * 16 + l15;
                int jb = (kk * 4 + quad) ^ (rb & 7);
                bfr[jj] = *(const bf16x8*)(Bl + rb * 64 + jb * 8);
            }
            {
                int rw = wn * 16 + l15;
                int jw = (kk * 4 + quad) ^ (rw & 7);
                wfr = *(const bf16x8*)(Wl + rw * 64 + jw * 8);
            }
            #pragma unroll
            for (int i = 0; i < 4; ++i) {
                int rr = wm * 64 + i * 16 + l15;
                int ja = (kk * 4 + quad) ^ (rr & 7);
                bf16x8 af = *(const bf16x8*)(Al + rr * 64 + ja * 8);
                #pragma unroll
                for (int jj = 0; jj < 2; ++jj)
                    acc[i][jj] = __builtin_amdgcn_mfma_f32_16x16x32_bf16(
                        af, bfr[jj], acc[i][jj], 0, 0, 0);
                accP[i] = __builtin_amdgcn_mfma_f32_16x16x32_bf16(
                    af, wfr, accP[i], 0, 0, 0);
            }
        }
        __syncthreads();
    }

    {
        const int p = wn * 8 + (l15 >> 1);
        const float bB = b2[p], bC = b3[p];
        #pragma unroll
        for (int i = 0; i < 4; ++i) {
            float sacc[4];
            #pragma unroll
            for (int r = 0; r < 4; ++r) {
                float v = accP[i][r];
                float pv = __shfl_xor(v, 1, 64);
                sacc[r] = (l15 & 1) ? (pv + bB) * (v + bC)
                                    : (v + bB) * (pv + bC);
                sacc[r] += __shfl_xor(sacc[r], 1, 64);
                sacc[r] += __shfl_xor(sacc[r], 2, 64);
                sacc[r] += __shfl_xor(sacc[r], 4, 64);
                sacc[r] += __shfl_xor(sacc[r], 8, 64);
            }
            if (l15 == 0) {
                #pragma unroll
                for (int r = 0; r < 4; ++r)
                    spart[wn][wm * 64 + i * 16 + quad * 4 + r] = 0.5f * sacc[r];
            }
        }
    }
    __syncthreads();

    #pragma unroll
    for (int i = 0; i < 4; ++i) {
        const int rl = wm * 64 + i * 16 + quad * 4;
        const int rowbase = m0 + rl;
        float sv4[4];
        #pragma unroll
        for (int r = 0; r < 4; ++r)
            sv4[r] = spart[0][rl + r] + spart[1][rl + r];
        #pragma unroll
        for (int jj = 0; jj < 2; ++jj) {
            int gcol = n0 + wn * 32 + jj * 16 + l15;
            float bias = b1[gcol];
            #pragma unroll
            for (int r = 0; r < 4; ++r) {
                int grow = rowbase + r;
                float v = acc[i][jj][r] + bias;
                float sp = softplus_fast(v);
                float xv = bf2f(xb[grow * DM + gcol]);
                y[grow * DM + gcol] = xv * sp * sv4[r];
            }
        }
    }
}

extern "C" void kernel_launch(void* const* d_in, const int* in_sizes, int n_in,
                              void* d_out, int out_size, void* d_ws, size_t ws_size,
                              hipStream_t stream) {
    const float* x  = (const float*)d_in[0];
    const float* W1 = (const float*)d_in[1];
    const float* b1 = (const float*)d_in[2];
    const float* W2 = (const float*)d_in[3];
    const float* b2 = (const float*)d_in[4];
    const float* W3 = (const float*)d_in[5];
    const float* b3 = (const float*)d_in[6];
    float* y = (float*)d_out;

    unsigned short* xb   = (unsigned short*)d_ws;                      // 12,582,912 B
    unsigned short* w1t  = (unsigned short*)((char*)d_ws + 12582912);  //  1,179,648 B
    unsigned short* w23t = (unsigned short*)((char*)d_ws + 13762560);  //     49,152 B
    float* scr0 = (float*)((char*)d_ws + 32 * 1024 * 1024);
    float* scr1 = (float*)((char*)d_ws + 34 * 1024 * 1024);
    float* scr2 = (float*)((char*)d_ws + 36 * 1024 * 1024);

    prep_kernel<<<6752, 256, 0, stream>>>(x, W1, W2, W3, xb, w1t, w23t);
    // probes (order: stage x3, compute x4, full-no-epi x2), then real kernel
    probe_kernel<2, 3><<<768, 256, 0, stream>>>(xb, w1t, w23t, b2, b3, scr0);
    probe_kernel<3, 4><<<768, 256, 0, stream>>>(xb, w1t, w23t, b2, b3, scr1);
    probe_kernel<1, 2><<<768, 256, 0, stream>>>(xb, w1t, w23t, b2, b3, scr2);
    gemm_fused_kernel<<<768, 256, 0, stream>>>(xb, w1t, w23t, b1, b2, b3, y);
}

// Round 8
// 114.811 us; speedup vs baseline: 1.9152x; 1.9152x over previous
//
#include <hip/hip_runtime.h>
#include <hip/hip_bf16.h>
#include <math.h>

// Problem: B=4, L=2048 (M = 8192 rows), D_MODEL = 768, N_STATE = 16.
// y[row,d] = x[row,d] * softplus((x@W1+b1)[row,d]) * dot(x@W2+b2, x@W3+b3)[row]
// Ledger: ~44 us harness fill per iter (fixed). R11 (112.1, best): xb
// precompute + single-buffer async16 k-loop, 128x64 tile. R13/R16/R17:
// sync-structure attacks all null. R18 ABLATION (probe dispatches, cutoff
// logic): stage <=14/rep, compute <=11/rep, FULL K-LOOP <=22/rep vs real
// gemm ~43 -> THE EPILOGUE IS ~17-22 us (~half the kernel): 32 scalar 2B
// xb loads + 32 scalar 4B y stores per thread, 64B half-line store granules
// (fill proves 6.1 TB/s with full lines; epilogue gets ~1.3 TB/s).
// R19 (this round): epilogue IO overhaul. k-loop VERBATIM. Epilogue bounces
// t = softplus(acc+b1)*sv through an 8 KB LDS tile (overlays dead Bl, no
// occupancy change), then streams out: per thread one bf16x8 xb load + two
// float4 y stores per i-tile — every global transaction a full 128B line.

#define M_ROWS 8192
#define DM 768
#define NS 16

typedef short bf16x8 __attribute__((ext_vector_type(8)));
typedef float f32x4 __attribute__((ext_vector_type(4)));

__device__ __forceinline__ unsigned short f2bf(float f) {
    union { float f; unsigned u; } v; v.f = f;
    unsigned r = v.u + 0x7FFF + ((v.u >> 16) & 1);   // RNE
    return (unsigned short)(r >> 16);
}
__device__ __forceinline__ float bf2f(unsigned short h) {
    union { unsigned u; float f; } v; v.u = ((unsigned)h) << 16; return v.f;
}
__device__ __forceinline__ void async16(const void* g, void* l) {
    __builtin_amdgcn_global_load_lds(
        (const __attribute__((address_space(1))) void*)g,
        (__attribute__((address_space(3))) void*)l,
        16, 0, 0);
}
// branchless stable softplus: max(v,0) + log(1+exp(-|v|)); HW exp/log.
__device__ __forceinline__ float softplus_fast(float v) {
    return fmaxf(v, 0.f) + __logf(1.f + __expf(-fabsf(v)));
}

// ---- kernel 1: prep (R0-verbatim) ---------------------------------------
// bid [0,32):      w23t build (bf16 n-major, pair-interleaved W2/W3 cols).
// bid [32,608):    W1 [k][n] fp32 -> w1t [n][k] bf16 (32x32 LDS tiles).
// bid [608,6752):  streaming convert x -> xb (bf16), float4/thread.
__global__ __launch_bounds__(256) void prep_kernel(
    const float* __restrict__ x,
    const float* __restrict__ W1,
    const float* __restrict__ W2,
    const float* __restrict__ W3,
    unsigned short* __restrict__ xb,
    unsigned short* __restrict__ w1t,
    unsigned short* __restrict__ w23t)
{
    __shared__ float tile[32][33];
    const int bid = blockIdx.x;
    const int tid = threadIdx.x;
    if (bid < 32) {
        const int n = bid, i = n >> 1;
        const float* src = (n & 1) ? W3 : W2;
        #pragma unroll
        for (int e = 0; e < 3; ++e) {
            int k = e * 256 + tid;
            w23t[n * DM + k] = f2bf(src[k * NS + i]);
        }
    } else if (bid < 608) {
        const int b2i = bid - 32;                // 0..575
        const int n0 = (b2i % 24) * 32, k0 = (b2i / 24) * 32;
        const int tx = tid & 31, ty = tid >> 5;  // 32 x 8
        #pragma unroll
        for (int i = 0; i < 4; ++i) {
            int k = ty + i * 8;
            tile[k][tx] = W1[(k0 + k) * DM + n0 + tx];
        }
        __syncthreads();
        #pragma unroll
        for (int i = 0; i < 4; ++i) {
            int n = ty + i * 8;
            w1t[(n0 + n) * DM + k0 + tx] = f2bf(tile[tx][n]);
        }
    } else {
        int i = (bid - 608) * 256 + tid;         // one float4 per thread
        float4 v = ((const float4*)x)[i];
        ushort4 o;
        o.x = f2bf(v.x); o.y = f2bf(v.y); o.z = f2bf(v.z); o.w = f2bf(v.w);
        ((ushort4*)xb)[i] = o;
    }
}

// ---- kernel 2: R11-verbatim k-loop + LDS-bounce streaming epilogue ------
__global__ __launch_bounds__(256) void gemm_fused_kernel(
    const unsigned short* __restrict__ xb,    // [8192][768] bf16
    const unsigned short* __restrict__ w1t,   // [768][768] bf16, n-major
    const unsigned short* __restrict__ w23t,  // [32][768] bf16, pair-interleaved
    const float* __restrict__ b1,
    const float* __restrict__ b2, const float* __restrict__ b3,
    float* __restrict__ y)
{
    // manual carve so ytile can overlay the dead Bl region post-k-loop
    __shared__ __align__(16) char smem[29696];               // 29 KB
    unsigned short* Al    = (unsigned short*)(smem);         // 16 KB
    unsigned short* Bl    = (unsigned short*)(smem + 16384); //  8 KB
    unsigned short* Wl    = (unsigned short*)(smem + 24576); //  4 KB
    float*          spart = (float*)(smem + 28672);          //  1 KB [2][128]
    float*          ytile = (float*)(smem + 16384);          //  8 KB overlays Bl

    const int b = blockIdx.x;
    const int c = b & 7, j = b >> 3;          // j in [0,96)
    const int m0 = (c * 8 + j / 12) * 128;
    const int n0 = (j % 12) * 64;
    const int tid  = threadIdx.x;
    const int lane = tid & 63;
    const int wave = tid >> 6;
    const int wm = wave >> 1, wn = wave & 1;
    const int l15 = lane & 15, quad = lane >> 4;

    f32x4 acc[4][2];
    f32x4 accP[4];
    #pragma unroll
    for (int i = 0; i < 4; ++i) {
        accP[i] = (f32x4){0.f, 0.f, 0.f, 0.f};
        #pragma unroll
        for (int jj = 0; jj < 2; ++jj)
            acc[i][jj] = (f32x4){0.f, 0.f, 0.f, 0.f};
    }

    for (int k0 = 0; k0 < DM; k0 += 64) {
        #pragma unroll
        for (int i = 0; i < 4; ++i) {         // A: 1024 chunks
            int ch = tid + i * 256;
            int r = ch >> 3, jg = (ch & 7) ^ (r & 7);
            async16(xb + (m0 + r) * DM + k0 + jg * 8, Al + ch * 8);
        }
        #pragma unroll
        for (int i = 0; i < 2; ++i) {         // B: 512 chunks
            int ch = tid + i * 256;
            int r = ch >> 3, jg = (ch & 7) ^ (r & 7);
            async16(w1t + (n0 + r) * DM + k0 + jg * 8, Bl + ch * 8);
        }
        {                                      // W23: 256 chunks
            int ch = tid;
            int r = ch >> 3, jg = (ch & 7) ^ (r & 7);
            async16(w23t + r * DM + k0 + jg * 8, Wl + ch * 8);
        }
        __syncthreads();

        #pragma unroll
        for (int kk = 0; kk < 2; ++kk) {
            bf16x8 bfr[2], wfr;
            #pragma unroll
            for (int jj = 0; jj < 2; ++jj) {
                int rb = wn * 32 + jj * 16 + l15;
                int jb = (kk * 4 + quad) ^ (rb & 7);
                bfr[jj] = *(const bf16x8*)(Bl + rb * 64 + jb * 8);
            }
            {
                int rw = wn * 16 + l15;
                int jw = (kk * 4 + quad) ^ (rw & 7);
                wfr = *(const bf16x8*)(Wl + rw * 64 + jw * 8);
            }
            #pragma unroll
            for (int i = 0; i < 4; ++i) {
                int rr = wm * 64 + i * 16 + l15;
                int ja = (kk * 4 + quad) ^ (rr & 7);
                bf16x8 af = *(const bf16x8*)(Al + rr * 64 + ja * 8);
                #pragma unroll
                for (int jj = 0; jj < 2; ++jj)
                    acc[i][jj] = __builtin_amdgcn_mfma_f32_16x16x32_bf16(
                        af, bfr[jj], acc[i][jj], 0, 0, 0);
                accP[i] = __builtin_amdgcn_mfma_f32_16x16x32_bf16(
                    af, wfr, accP[i], 0, 0, 0);
            }
        }
        __syncthreads();
    }

    // ---- s partials: this wave owns pairs p = wn*8 + (l15>>1) ----
    {
        const int p = wn * 8 + (l15 >> 1);
        const float bB = b2[p], bC = b3[p];
        #pragma unroll
        for (int i = 0; i < 4; ++i) {
            float sacc[4];
            #pragma unroll
            for (int r = 0; r < 4; ++r) {
                float v = accP[i][r];
                float pv = __shfl_xor(v, 1, 64);
                sacc[r] = (l15 & 1) ? (pv + bB) * (v + bC)
                                    : (v + bB) * (pv + bC);
                sacc[r] += __shfl_xor(sacc[r], 1, 64);
                sacc[r] += __shfl_xor(sacc[r], 2, 64);
                sacc[r] += __shfl_xor(sacc[r], 4, 64);
                sacc[r] += __shfl_xor(sacc[r], 8, 64);
            }
            if (l15 == 0) {
                #pragma unroll
                for (int r = 0; r < 4; ++r)
                    spart[wn * 128 + wm * 64 + i * 16 + quad * 4 + r] = 0.5f * sacc[r];
            }
        }
    }
    __syncthreads();

    // ---- epilogue: LDS bounce -> fully-coalesced streaming IO ----
    // writer: fragment layout (col=l15, row=quad*4+r) computes
    //   t = softplus(acc+b1)*sv into ytile[32][64] (rows = wm*16+quad*4+r).
    // reader: thread tid owns row_l=tid>>3, cols cg*8..cg*8+7 -> one bf16x8
    //   xb load + two float4 y stores, all 128B-line transactions.
    const int row_l = tid >> 3;              // 0..31
    const int cg    = tid & 7;               // 0..7
    const int grow_base = m0 + (row_l >> 4) * 64 + (row_l & 15);
    const int gcol_r    = n0 + cg * 8;
    #pragma unroll
    for (int i = 0; i < 4; ++i) {
        // writer phase
        const int rl = wm * 64 + i * 16 + quad * 4;
        float sv4[4];
        #pragma unroll
        for (int r = 0; r < 4; ++r)
            sv4[r] = spart[rl + r] + spart[128 + rl + r];
        #pragma unroll
        for (int jj = 0; jj < 2; ++jj) {
            const int tc = wn * 32 + jj * 16 + l15;
            const float bias = b1[n0 + tc];
            #pragma unroll
            for (int r = 0; r < 4; ++r) {
                float v = acc[i][jj][r] + bias;
                float sp = softplus_fast(v);
                ytile[(wm * 16 + quad * 4 + r) * 64 + tc] = sp * sv4[r];
            }
        }
        __syncthreads();
        // reader phase
        const int grow = grow_base + i * 16;
        f32x4 t0 = *(const f32x4*)&ytile[row_l * 64 + cg * 8];
        f32x4 t1 = *(const f32x4*)&ytile[row_l * 64 + cg * 8 + 4];
        bf16x8 xv8 = *(const bf16x8*)(xb + grow * DM + gcol_r);
        f32x4 o0, o1;
        #pragma unroll
        for (int e = 0; e < 4; ++e) {
            o0[e] = t0[e] * bf2f((unsigned short)xv8[e]);
            o1[e] = t1[e] * bf2f((unsigned short)xv8[e + 4]);
        }
        *(f32x4*)(y + grow * DM + gcol_r)     = o0;
        *(f32x4*)(y + grow * DM + gcol_r + 4) = o1;
        if (i < 3) __syncthreads();          // ytile reused next i-tile
    }
}

extern "C" void kernel_launch(void* const* d_in, const int* in_sizes, int n_in,
                              void* d_out, int out_size, void* d_ws, size_t ws_size,
                              hipStream_t stream) {
    const float* x  = (const float*)d_in[0];
    const float* W1 = (const float*)d_in[1];
    const float* b1 = (const float*)d_in[2];
    const float* W2 = (const float*)d_in[3];
    const float* b2 = (const float*)d_in[4];
    const float* W3 = (const float*)d_in[5];
    const float* b3 = (const float*)d_in[6];
    // d_in[7] = A : unused (multiplied by h0 == 0 in the reference)
    float* y = (float*)d_out;

    unsigned short* xb   = (unsigned short*)d_ws;                      // 12,582,912 B
    unsigned short* w1t  = (unsigned short*)((char*)d_ws + 12582912);  //  1,179,648 B
    unsigned short* w23t = (unsigned short*)((char*)d_ws + 13762560);  //     49,152 B

    prep_kernel<<<6752, 256, 0, stream>>>(x, W1, W2, W3, xb, w1t, w23t);
    gemm_fused_kernel<<<768, 256, 0, stream>>>(xb, w1t, w23t, b1, b2, b3, y);
}